// Round 1
// baseline (33.660 us; speedup 1.0000x reference)
//
#include <hip/hip_runtime.h>

// Cl(3,0) geometric product, blades in short-lex order:
//   idx: 0=1, 1=e1, 2=e2, 3=e3, 4=e12, 5=e13, 6=e23, 7=e123
// out[j] = sum_{i,k} a[i] * C[i,j,k] * b[k], C has 64 nonzeros (+-1), hard-coded below.

__global__ __launch_bounds__(256) void clifford_gp_kernel(
    const float* __restrict__ A, const float* __restrict__ B,
    float* __restrict__ O, int n_mv)
{
    int idx = blockIdx.x * 256 + threadIdx.x;
    if (idx >= n_mv) return;

    const float4* A4 = reinterpret_cast<const float4*>(A) + (size_t)idx * 2;
    const float4* B4 = reinterpret_cast<const float4*>(B) + (size_t)idx * 2;
    float4 al = A4[0], ah = A4[1];
    float4 bl = B4[0], bh = B4[1];

    float a0=al.x, a1=al.y, a2=al.z, a3=al.w, a4=ah.x, a5=ah.y, a6=ah.z, a7=ah.w;
    float b0=bl.x, b1=bl.y, b2=bl.z, b3=bl.w, b4=bh.x, b5=bh.y, b6=bh.z, b7=bh.w;

    float4 ol, oh;
    // scalar
    ol.x = a0*b0 + a1*b1 + a2*b2 + a3*b3 - a4*b4 - a5*b5 - a6*b6 - a7*b7;
    // e1
    ol.y = a0*b1 + a1*b0 - a2*b4 - a3*b5 + a4*b2 + a5*b3 - a6*b7 - a7*b6;
    // e2
    ol.z = a0*b2 + a1*b4 + a2*b0 - a3*b6 - a4*b1 + a5*b7 + a6*b3 + a7*b5;
    // e3
    ol.w = a0*b3 + a1*b5 + a2*b6 + a3*b0 - a4*b7 - a5*b1 - a6*b2 - a7*b4;
    // e12
    oh.x = a0*b4 + a1*b2 - a2*b1 + a3*b7 + a4*b0 - a5*b6 + a6*b5 + a7*b3;
    // e13
    oh.y = a0*b5 + a1*b3 - a2*b7 - a3*b1 + a4*b6 + a5*b0 - a6*b4 - a7*b2;
    // e23
    oh.z = a0*b6 + a1*b7 + a2*b3 - a3*b2 - a4*b5 + a5*b4 + a6*b0 + a7*b1;
    // e123
    oh.w = a0*b7 + a1*b6 - a2*b5 + a3*b4 + a4*b3 - a5*b2 + a6*b1 + a7*b0;

    float4* O4 = reinterpret_cast<float4*>(O) + (size_t)idx * 2;
    O4[0] = ol;
    O4[1] = oh;
}

extern "C" void kernel_launch(void* const* d_in, const int* in_sizes, int n_in,
                              void* d_out, int out_size, void* d_ws, size_t ws_size,
                              hipStream_t stream) {
    const float* a = (const float*)d_in[0];
    const float* b = (const float*)d_in[1];
    // d_in[2] is the cayley table; it is a compile-time constant for Cl(3,0), hard-coded.
    float* out = (float*)d_out;

    int n_mv = in_sizes[0] / 8;  // 2048*1024 = 2097152 multivectors
    int blocks = (n_mv + 255) / 256;
    clifford_gp_kernel<<<blocks, 256, 0, stream>>>(a, b, out, n_mv);
}